// Round 1
// baseline (5870.912 us; speedup 1.0000x reference)
//
#include <hip/hip_runtime.h>
#include <hip/hip_bf16.h>
#include <math.h>

typedef short s16x8 __attribute__((ext_vector_type(8)));
typedef float f32x4 __attribute__((ext_vector_type(4)));
typedef unsigned short u16;

// ---------- helpers ----------
__device__ __forceinline__ u16 f2b(float f) {
    unsigned u = __builtin_bit_cast(unsigned, f);
    u += 0x7fffu + ((u >> 16) & 1u);           // round-to-nearest-even
    return (u16)(u >> 16);
}
__device__ __forceinline__ float b2f(u16 h) {
    unsigned u = ((unsigned)h) << 16;
    return __builtin_bit_cast(float, u);
}
__device__ __forceinline__ f32x4 mfma16(s16x8 a, s16x8 b, f32x4 c) {
    return __builtin_amdgcn_mfma_f32_16x16x32_bf16(a, b, c, 0, 0, 0);
}
__device__ __forceinline__ void gload16(const void* g, void* l) {
    __builtin_amdgcn_global_load_lds((const __attribute__((address_space(1))) unsigned*)g,
                                     (__attribute__((address_space(3))) unsigned*)l, 16, 0, 0);
}

// ---------- patchify: x (32,64,32,32) f32 -> patchA (8192,256) bf16 ----------
__global__ __launch_bounds__(256) void patchify_kernel(const float* __restrict__ x, u16* __restrict__ out) {
    int idx = blockIdx.x * 256 + threadIdx.x;           // 0 .. 2M-1
    int row = idx >> 8, col = idx & 255;
    int b = row >> 8, ll = row & 255, hp = ll >> 4, wp = ll & 15;
    int pp = col >> 6, d = col & 63;
    out[idx] = f2b(x[(size_t)((b * 64 + d) * 32 + hp * 2 + (pp >> 1)) * 32 + wp * 2 + (pp & 1)]);
}

// ---------- c_act = silu(timestep_emb + emb_table[y]) -> bf16 (32,1024) ----------
__global__ __launch_bounds__(256) void cact_kernel(const int* __restrict__ t, const int* __restrict__ y,
                                                   const float* __restrict__ emb, u16* __restrict__ cact) {
    int b = blockIdx.x, tid = threadIdx.x;
    float tv = (float)t[b];
    int yb = y[b];
#pragma unroll
    for (int j = 0; j < 4; ++j) {
        int c = tid * 4 + j;
        int f = (c < 512) ? c : c - 512;
        float freq = __expf(-9.210340371976184f * (float)f * (1.f / 512.f));  // ln(10000)
        float ang = tv * freq;
        float v = (c < 512) ? cosf(ang) : sinf(ang);
        v += emb[(size_t)yb * 1024 + c];
        v = v / (1.f + __expf(-v));   // silu
        cact[b * 1024 + c] = f2b(v);
    }
}

// ---------- concat q/k/v biases for all 12 layers -> (12,3072) f32 ----------
__global__ __launch_bounds__(256) void bcat_kernel(const float* __restrict__ bq, const float* __restrict__ bk,
                                                   const float* __restrict__ bv, float* __restrict__ out) {
    int lyr = blockIdx.x, j = blockIdx.y, tid = threadIdx.x;
    const float* src = (j == 0) ? bq : ((j == 1) ? bk : bv);
    float4 v = ((const float4*)(src + (size_t)lyr * 1024))[tid];
    ((float4*)(out + (size_t)lyr * 3072 + j * 1024))[tid] = v;
}

// ---------- transpose+convert: in (R,C) f32 -> out (C,R) bf16 ----------
__global__ __launch_bounds__(256) void transpose_cvt(const float* __restrict__ in, u16* __restrict__ out,
                                                     int R, int C) {
    __shared__ float tile[32][33];
    int c0 = blockIdx.x * 32, r0 = blockIdx.y * 32;
    int tid = threadIdx.x;
#pragma unroll
    for (int j = 0; j < 4; ++j) {
        int i = tid + j * 256;
        int r = i >> 5, c = i & 31;
        tile[r][c] = in[(size_t)(r0 + r) * C + c0 + c];
    }
    __syncthreads();
#pragma unroll
    for (int j = 0; j < 4; ++j) {
        int i = tid + j * 256;
        int r = i >> 5, c = i & 31;
        out[(size_t)(c0 + r) * R + r0 + c] = f2b(tile[c][r]);
    }
}

// ---------- LayerNorm + modulate: hx = ln(x)*(1+sc)+sh -> bf16 ----------
__global__ __launch_bounds__(256) void ln_mod_kernel(const float* __restrict__ x, const float* __restrict__ modv,
                                                     int mod_ld, int sh_off, int sc_off, u16* __restrict__ out) {
    int row = blockIdx.x, tid = threadIdx.x, b = row >> 8;
    float4 xv = ((const float4*)(x + (size_t)row * 1024))[tid];
    float s = xv.x + xv.y + xv.z + xv.w;
    float s2 = xv.x * xv.x + xv.y * xv.y + xv.z * xv.z + xv.w * xv.w;
#pragma unroll
    for (int d = 1; d < 64; d <<= 1) { s += __shfl_xor(s, d); s2 += __shfl_xor(s2, d); }
    __shared__ float red[8];
    int w = tid >> 6;
    if ((tid & 63) == 0) { red[w] = s; red[4 + w] = s2; }
    __syncthreads();
    s = red[0] + red[1] + red[2] + red[3];
    s2 = red[4] + red[5] + red[6] + red[7];
    float mu = s * (1.f / 1024.f);
    float rs = rsqrtf(s2 * (1.f / 1024.f) - mu * mu + 1e-5f);
    const float* shp = modv + (size_t)b * mod_ld + sh_off;
    const float* scp = modv + (size_t)b * mod_ld + sc_off;
    float4 sh4 = ((const float4*)shp)[tid];
    float4 sc4 = ((const float4*)scp)[tid];
    u16 o0 = f2b((xv.x - mu) * rs * (1.f + sc4.x) + sh4.x);
    u16 o1 = f2b((xv.y - mu) * rs * (1.f + sc4.y) + sh4.y);
    u16 o2 = f2b((xv.z - mu) * rs * (1.f + sc4.z) + sh4.z);
    u16 o3 = f2b((xv.w - mu) * rs * (1.f + sc4.w) + sh4.w);
    unsigned long long pk = (unsigned long long)o0 | ((unsigned long long)o1 << 16) |
                            ((unsigned long long)o2 << 32) | ((unsigned long long)o3 << 48);
    *(unsigned long long*)&out[(size_t)row * 1024 + tid * 4] = pk;
}

// ---------- GEMM: C = A(MxK,bf16) * B^T(NxK,bf16), templated epilogue ----------
// EPI 0: outF = acc + bias[col]
// EPI 1: outB = bf16(acc + bias[col])
// EPI 2: outF = acc + bias[col] + pos[(row&255)*1024+col]
// EPI 3: outF = aux1[row,col] + aux2[b*6144+gateOff+col]*(acc+bias[col])   (residual, in-place ok)
// EPI 4: outB = bf16(gelu_exact(acc + bias[col]))
// EPI 5: unpatchify scatter f32
template <int EPI>
__global__ __launch_bounds__(256, 2) void gemm_k(
    const u16* __restrict__ A, int lda, const u16* __restrict__ Bt, int ldb,
    int M, int N, int K, const float* __restrict__ bias,
    float* outF, u16* __restrict__ outB, int ldc,
    const float* aux1, const float* __restrict__ aux2, int gateOff) {
    __shared__ u16 As[128 * 32];
    __shared__ u16 Bs[128 * 32];
    const int tid = threadIdx.x, w = tid >> 6, l = tid & 63;
    const int row0 = blockIdx.y * 128, col0 = blockIdx.x * 128;
    const int wm = w >> 1, wn = w & 1;

    f32x4 acc[4][4];
#pragma unroll
    for (int m = 0; m < 4; ++m)
#pragma unroll
        for (int n = 0; n < 4; ++n) acc[m][n] = (f32x4){0.f, 0.f, 0.f, 0.f};

    const int rA0 = w * 16 + (l >> 2), rA1 = rA0 + 64;
    const int kc = (l & 3) * 8;
    int gr0 = row0 + rA0; if (gr0 > M - 1) gr0 = M - 1;
    int gr1 = row0 + rA1; if (gr1 > M - 1) gr1 = M - 1;
    const u16* a0 = A + (size_t)gr0 * lda + kc;
    const u16* a1 = A + (size_t)gr1 * lda + kc;
    const u16* b0 = Bt + (size_t)(col0 + rA0) * ldb + kc;
    const u16* b1 = Bt + (size_t)(col0 + rA1) * ldb + kc;
    u16* la0 = &As[rA0 * 32 + kc];
    u16* la1 = &As[rA1 * 32 + kc];
    u16* lb0 = &Bs[rA0 * 32 + kc];
    u16* lb1 = &Bs[rA1 * 32 + kc];

    for (int k0 = 0; k0 < K; k0 += 32) {
        __syncthreads();
        gload16(a0 + k0, la0);
        gload16(a1 + k0, la1);
        gload16(b0 + k0, lb0);
        gload16(b1 + k0, lb1);
        __syncthreads();
        s16x8 af[4], bfr[4];
#pragma unroll
        for (int m = 0; m < 4; ++m)
            af[m] = *(const s16x8*)&As[(wm * 64 + m * 16 + (l & 15)) * 32 + (l >> 4) * 8];
#pragma unroll
        for (int n = 0; n < 4; ++n)
            bfr[n] = *(const s16x8*)&Bs[(wn * 64 + n * 16 + (l & 15)) * 32 + (l >> 4) * 8];
#pragma unroll
        for (int m = 0; m < 4; ++m)
#pragma unroll
            for (int n = 0; n < 4; ++n) acc[m][n] = mfma16(af[m], bfr[n], acc[m][n]);
    }

#pragma unroll
    for (int m = 0; m < 4; ++m) {
#pragma unroll
        for (int n = 0; n < 4; ++n) {
#pragma unroll
            for (int r = 0; r < 4; ++r) {
                int row = row0 + wm * 64 + m * 16 + (l >> 4) * 4 + r;
                if (row >= M) continue;
                int col = col0 + wn * 64 + n * 16 + (l & 15);
                float v = acc[m][n][r];
                if constexpr (EPI == 0) {
                    outF[(size_t)row * ldc + col] = v + bias[col];
                } else if constexpr (EPI == 1) {
                    outB[(size_t)row * ldc + col] = f2b(v + bias[col]);
                } else if constexpr (EPI == 2) {
                    outF[(size_t)row * ldc + col] = v + bias[col] + aux1[(size_t)(row & 255) * 1024 + col];
                } else if constexpr (EPI == 3) {
                    outF[(size_t)row * ldc + col] =
                        aux1[(size_t)row * ldc + col] +
                        aux2[(size_t)(row >> 8) * 6144 + gateOff + col] * (v + bias[col]);
                } else if constexpr (EPI == 4) {
                    float xg = v + bias[col];
                    outB[(size_t)row * ldc + col] = f2b(0.5f * xg * (1.f + erff(xg * 0.70710678118654752f)));
                } else {  // EPI == 5: unpatchify
                    float xg = v + bias[col];
                    int bb = row >> 8, ll = row & 255, hp = ll >> 4, wp = ll & 15;
                    int pp = col >> 6, d = col & 63;
                    outF[(size_t)((bb * 64 + d) * 32 + hp * 2 + (pp >> 1)) * 32 + wp * 2 + (pp & 1)] = xg;
                }
            }
        }
    }
}

// ---------- attention: qkv (8192,3072) bf16 -> obuf (8192,1024) bf16 ----------
// grid (qt=4, h=16, b=32); 4 waves; wave w owns 16 query rows.
__global__ __launch_bounds__(256, 2) void attn_kernel(const u16* __restrict__ qkv, u16* __restrict__ obuf) {
    __shared__ u16 Qs[64 * 64];     // [qrow][dh]
    __shared__ u16 Ks[256 * 64];    // [ktok][dh]; reused later as P [qrow][ktok]
    __shared__ u16 VTs[64 * 256];   // [dh][ktok]
    int qt = blockIdx.x, h = blockIdx.y, b = blockIdx.z;
    int tid = threadIdx.x, w = tid >> 6, l = tid & 63;
    size_t base = (size_t)b * 256 * 3072;

    {   // Q: 64 rows x 64 cols
        int r = tid >> 2;
#pragma unroll
        for (int j = 0; j < 2; ++j) {
            int sg = (tid & 3) + j * 4;
            *(s16x8*)&Qs[r * 64 + sg * 8] =
                *(const s16x8*)&qkv[base + (size_t)(qt * 64 + r) * 3072 + h * 64 + sg * 8];
        }
    }
#pragma unroll
    for (int j = 0; j < 8; ++j) {   // K: 256 x 64
        int i = tid + j * 256;
        int r = i >> 3, sg = i & 7;
        *(s16x8*)&Ks[r * 64 + sg * 8] =
            *(const s16x8*)&qkv[base + (size_t)r * 3072 + 1024 + h * 64 + sg * 8];
    }
#pragma unroll
    for (int j = 0; j < 8; ++j) {   // V -> VT
        int i = tid + j * 256;
        int r = i >> 3, sg = i & 7;
        s16x8 v = *(const s16x8*)&qkv[base + (size_t)r * 3072 + 2048 + h * 64 + sg * 8];
#pragma unroll
        for (int e = 0; e < 8; ++e) VTs[(sg * 8 + e) * 256 + r] = ((const u16*)&v)[e];
    }
    __syncthreads();

    // scores S = Q K^T * 0.125 ; wave w -> rows w*16..+16, 16 col-fragments
    s16x8 aq0 = *(const s16x8*)&Qs[(w * 16 + (l & 15)) * 64 + (l >> 4) * 8];
    s16x8 aq1 = *(const s16x8*)&Qs[(w * 16 + (l & 15)) * 64 + 32 + (l >> 4) * 8];
    f32x4 sf[16];
#pragma unroll
    for (int cf = 0; cf < 16; ++cf) {
        f32x4 a = (f32x4){0.f, 0.f, 0.f, 0.f};
        s16x8 bk0 = *(const s16x8*)&Ks[(cf * 16 + (l & 15)) * 64 + (l >> 4) * 8];
        s16x8 bk1 = *(const s16x8*)&Ks[(cf * 16 + (l & 15)) * 64 + 32 + (l >> 4) * 8];
        a = mfma16(aq0, bk0, a);
        a = mfma16(aq1, bk1, a);
        sf[cf] = a * 0.125f;
    }
    __syncthreads();   // all waves done reading Ks before it becomes P

    // softmax rows; write P (bf16) into Ks storage as [qrow][ktok]
#pragma unroll
    for (int r = 0; r < 4; ++r) {
        float m = -1e30f;
#pragma unroll
        for (int cf = 0; cf < 16; ++cf) m = fmaxf(m, sf[cf][r]);
#pragma unroll
        for (int d = 1; d < 16; d <<= 1) m = fmaxf(m, __shfl_xor(m, d));
        float sm = 0.f;
#pragma unroll
        for (int cf = 0; cf < 16; ++cf) { float e = __expf(sf[cf][r] - m); sf[cf][r] = e; sm += e; }
#pragma unroll
        for (int d = 1; d < 16; d <<= 1) sm += __shfl_xor(sm, d);
        float inv = 1.f / sm;
        int rl = w * 16 + (l >> 4) * 4 + r;
#pragma unroll
        for (int cf = 0; cf < 16; ++cf) Ks[rl * 256 + cf * 16 + (l & 15)] = f2b(sf[cf][r] * inv);
    }
    __syncthreads();

    // O = P V : wave w -> rows w*16..+16, cols 64 (4 fragments), K=256 (8 slices)
    f32x4 oacc[4];
#pragma unroll
    for (int cf = 0; cf < 4; ++cf) oacc[cf] = (f32x4){0.f, 0.f, 0.f, 0.f};
#pragma unroll
    for (int ks = 0; ks < 8; ++ks) {
        s16x8 ap = *(const s16x8*)&Ks[(w * 16 + (l & 15)) * 256 + ks * 32 + (l >> 4) * 8];
#pragma unroll
        for (int cf = 0; cf < 4; ++cf) {
            s16x8 bv = *(const s16x8*)&VTs[(cf * 16 + (l & 15)) * 256 + ks * 32 + (l >> 4) * 8];
            oacc[cf] = mfma16(ap, bv, oacc[cf]);
        }
    }
    size_t orow0 = (size_t)(b * 256 + qt * 64 + w * 16);
#pragma unroll
    for (int cf = 0; cf < 4; ++cf)
#pragma unroll
        for (int r = 0; r < 4; ++r) {
            int rr = (l >> 4) * 4 + r;
            obuf[(orow0 + rr) * 1024 + h * 64 + cf * 16 + (l & 15)] = f2b(oacc[cf][r]);
        }
}

// ---------- host ----------
extern "C" void kernel_launch(void* const* d_in, const int* in_sizes, int n_in,
                              void* d_out, int out_size, void* d_ws, size_t ws_size,
                              hipStream_t stream) {
    (void)in_sizes; (void)n_in; (void)out_size; (void)ws_size;
    const float* x         = (const float*)d_in[0];
    const int*   y         = (const int*)d_in[1];
    const int*   t         = (const int*)d_in[2];
    const float* proj_w    = (const float*)d_in[3];
    const float* proj_b    = (const float*)d_in[4];
    const float* pos_embed = (const float*)d_in[5];
    const float* emb_table = (const float*)d_in[6];
    const float* blk_mod_w = (const float*)d_in[7];
    const float* blk_mod_b = (const float*)d_in[8];
    const float* blk_wq    = (const float*)d_in[9];
    const float* blk_bq    = (const float*)d_in[10];
    const float* blk_wk    = (const float*)d_in[11];
    const float* blk_bk    = (const float*)d_in[12];
    const float* blk_wv    = (const float*)d_in[13];
    const float* blk_bv    = (const float*)d_in[14];
    const float* blk_wo    = (const float*)d_in[15];
    const float* blk_bo    = (const float*)d_in[16];
    const float* blk_f1w   = (const float*)d_in[17];
    const float* blk_f1b   = (const float*)d_in[18];
    const float* blk_f2w   = (const float*)d_in[19];
    const float* blk_f2b   = (const float*)d_in[20];
    const float* fin_mod_w = (const float*)d_in[21];
    const float* fin_mod_b = (const float*)d_in[22];
    const float* fin_out_w = (const float*)d_in[23];
    const float* fin_out_b = (const float*)d_in[24];
    float* out = (float*)d_out;

    char* ws = (char*)d_ws;
    size_t off = 0;
    auto alloc = [&](size_t bytes) -> char* {
        char* p = ws + off;
        off += (bytes + 255) & ~(size_t)255;
        return p;
    };
    float* xc    = (float*)alloc(8192ull * 1024 * 4);
    u16*   hx    = (u16*)alloc(8192ull * 1024 * 2);
    u16*   qkvb  = (u16*)alloc(8192ull * 3072 * 2);
    u16*   obufp = (u16*)alloc(8192ull * 1024 * 2);
    u16*   h1    = (u16*)alloc(8192ull * 4096 * 2);
    u16*   patchA= (u16*)alloc(8192ull * 256 * 2);
    u16*   cact  = (u16*)alloc(32ull * 1024 * 2);
    float* modb  = (float*)alloc(32ull * 6144 * 4);
    float* fmod  = (float*)alloc(32ull * 2048 * 4);
    float* bqkv  = (float*)alloc(12ull * 3072 * 4);
    u16*   projT = (u16*)alloc(1024ull * 256 * 2);
    u16*   fmT   = (u16*)alloc(2048ull * 1024 * 2);
    u16*   foT   = (u16*)alloc(256ull * 1024 * 2);
    u16*   modT  = (u16*)alloc(6144ull * 1024 * 2);
    u16*   qkvT  = (u16*)alloc(3072ull * 1024 * 2);
    u16*   woT   = (u16*)alloc(1024ull * 1024 * 2);
    u16*   f1T   = (u16*)alloc(4096ull * 1024 * 2);
    u16*   f2T   = (u16*)alloc(1024ull * 4096 * 2);

    patchify_kernel<<<8192, 256, 0, stream>>>(x, patchA);
    cact_kernel<<<32, 256, 0, stream>>>(t, y, emb_table, cact);
    bcat_kernel<<<dim3(12, 3), 256, 0, stream>>>(blk_bq, blk_bk, blk_bv, bqkv);
    transpose_cvt<<<dim3(32, 8), 256, 0, stream>>>(proj_w, projT, 256, 1024);
    transpose_cvt<<<dim3(64, 32), 256, 0, stream>>>(fin_mod_w, fmT, 1024, 2048);
    transpose_cvt<<<dim3(8, 32), 256, 0, stream>>>(fin_out_w, foT, 1024, 256);

    // tok = patchA @ proj_w + b + pos  -> xc f32
    gemm_k<2><<<dim3(8, 64), 256, 0, stream>>>(patchA, 256, projT, 256, 8192, 1024, 256,
                                               proj_b, xc, nullptr, 1024, pos_embed, nullptr, 0);
    // fmod = c_act @ fin_mod_w + b
    gemm_k<0><<<dim3(16, 1), 256, 0, stream>>>(cact, 1024, fmT, 1024, 32, 2048, 1024,
                                               fin_mod_b, fmod, nullptr, 2048, nullptr, nullptr, 0);

    for (int i = 0; i < 12; ++i) {
        transpose_cvt<<<dim3(192, 32), 256, 0, stream>>>(blk_mod_w + (size_t)i * 1024 * 6144, modT, 1024, 6144);
        transpose_cvt<<<dim3(32, 32), 256, 0, stream>>>(blk_wq + (size_t)i * 1024 * 1024, qkvT, 1024, 1024);
        transpose_cvt<<<dim3(32, 32), 256, 0, stream>>>(blk_wk + (size_t)i * 1024 * 1024, qkvT + 1024 * 1024, 1024, 1024);
        transpose_cvt<<<dim3(32, 32), 256, 0, stream>>>(blk_wv + (size_t)i * 1024 * 1024, qkvT + 2048 * 1024, 1024, 1024);
        transpose_cvt<<<dim3(32, 32), 256, 0, stream>>>(blk_wo + (size_t)i * 1024 * 1024, woT, 1024, 1024);
        transpose_cvt<<<dim3(128, 32), 256, 0, stream>>>(blk_f1w + (size_t)i * 1024 * 4096, f1T, 1024, 4096);
        transpose_cvt<<<dim3(32, 128), 256, 0, stream>>>(blk_f2w + (size_t)i * 4096 * 1024, f2T, 4096, 1024);

        // mod = c_act @ mod_w + mod_b   (32 x 6144)
        gemm_k<0><<<dim3(48, 1), 256, 0, stream>>>(cact, 1024, modT, 1024, 32, 6144, 1024,
                                                   blk_mod_b + (size_t)i * 6144, modb, nullptr, 6144,
                                                   nullptr, nullptr, 0);
        // hx = ln(xc)*(1+sc_a)+sh_a
        ln_mod_kernel<<<8192, 256, 0, stream>>>(xc, modb, 6144, 0, 1024, hx);
        // qkv = hx @ [wq|wk|wv] + biases  -> bf16
        gemm_k<1><<<dim3(24, 64), 256, 0, stream>>>(hx, 1024, qkvT, 1024, 8192, 3072, 1024,
                                                    bqkv + (size_t)i * 3072, nullptr, qkvb, 3072,
                                                    nullptr, nullptr, 0);
        attn_kernel<<<dim3(4, 16, 32), 256, 0, stream>>>(qkvb, obufp);
        // xc += g_a * (o @ wo + bo)
        gemm_k<3><<<dim3(8, 64), 256, 0, stream>>>(obufp, 1024, woT, 1024, 8192, 1024, 1024,
                                                   blk_bo + (size_t)i * 1024, xc, nullptr, 1024,
                                                   xc, modb, 2048);
        // hx = ln(xc)*(1+sc_m)+sh_m
        ln_mod_kernel<<<8192, 256, 0, stream>>>(xc, modb, 6144, 3072, 4096, hx);
        // h1 = gelu(hx @ f1 + b1)
        gemm_k<4><<<dim3(32, 64), 256, 0, stream>>>(hx, 1024, f1T, 1024, 8192, 4096, 1024,
                                                    blk_f1b + (size_t)i * 4096, nullptr, h1, 4096,
                                                    nullptr, nullptr, 0);
        // xc += g_m * (h1 @ f2 + b2)
        gemm_k<3><<<dim3(8, 64), 256, 0, stream>>>(h1, 4096, f2T, 4096, 8192, 1024, 4096,
                                                   blk_f2b + (size_t)i * 1024, xc, nullptr, 1024,
                                                   xc, modb, 5120);
    }
    // final: hx = ln(xc)*(1+sc)+sh ; out = unpatchify(hx @ fin_out_w + b)
    ln_mod_kernel<<<8192, 256, 0, stream>>>(xc, fmod, 2048, 0, 1024, hx);
    gemm_k<5><<<dim3(2, 64), 256, 0, stream>>>(hx, 1024, foT, 1024, 8192, 256, 1024,
                                               fin_out_b, out, nullptr, 256, nullptr, nullptr, 0);
}

// Round 2
// 5102.863 us; speedup vs baseline: 1.1505x; 1.1505x over previous
//
#include <hip/hip_runtime.h>
#include <hip/hip_bf16.h>
#include <math.h>

typedef short s16x8 __attribute__((ext_vector_type(8)));
typedef float f32x4 __attribute__((ext_vector_type(4)));
typedef unsigned short u16;

// ---------- helpers ----------
__device__ __forceinline__ u16 f2b(float f) {
    unsigned u = __builtin_bit_cast(unsigned, f);
    u += 0x7fffu + ((u >> 16) & 1u);           // round-to-nearest-even
    return (u16)(u >> 16);
}
__device__ __forceinline__ f32x4 mfma16(s16x8 a, s16x8 b, f32x4 c) {
    return __builtin_amdgcn_mfma_f32_16x16x32_bf16(a, b, c, 0, 0, 0);
}
__device__ __forceinline__ void gload16(const void* g, void* l) {
    __builtin_amdgcn_global_load_lds((const __attribute__((address_space(1))) unsigned*)g,
                                     (__attribute__((address_space(3))) unsigned*)l, 16, 0, 0);
}

// ---------- patchify: x (32,64,32,32) f32 -> patchA (8192,256) bf16 ----------
__global__ __launch_bounds__(256) void patchify_kernel(const float* __restrict__ x, u16* __restrict__ out) {
    int idx = blockIdx.x * 256 + threadIdx.x;
    int row = idx >> 8, col = idx & 255;
    int b = row >> 8, ll = row & 255, hp = ll >> 4, wp = ll & 15;
    int pp = col >> 6, d = col & 63;
    out[idx] = f2b(x[(size_t)((b * 64 + d) * 32 + hp * 2 + (pp >> 1)) * 32 + wp * 2 + (pp & 1)]);
}

// ---------- c_act = silu(timestep_emb + emb_table[y]) -> bf16 (32,1024) ----------
__global__ __launch_bounds__(256) void cact_kernel(const int* __restrict__ t, const int* __restrict__ y,
                                                   const float* __restrict__ emb, u16* __restrict__ cact) {
    int b = blockIdx.x, tid = threadIdx.x;
    float tv = (float)t[b];
    int yb = y[b];
#pragma unroll
    for (int j = 0; j < 4; ++j) {
        int c = tid * 4 + j;
        int f = (c < 512) ? c : c - 512;
        float freq = __expf(-9.210340371976184f * (float)f * (1.f / 512.f));
        float ang = tv * freq;
        float v = (c < 512) ? cosf(ang) : sinf(ang);
        v += emb[(size_t)yb * 1024 + c];
        v = v / (1.f + __expf(-v));   // silu
        cact[b * 1024 + c] = f2b(v);
    }
}

// ---------- concat q/k/v biases for all 12 layers -> (12,3072) f32 ----------
__global__ __launch_bounds__(256) void bcat_kernel(const float* __restrict__ bq, const float* __restrict__ bk,
                                                   const float* __restrict__ bv, float* __restrict__ out) {
    int lyr = blockIdx.x, j = blockIdx.y, tid = threadIdx.x;
    const float* src = (j == 0) ? bq : ((j == 1) ? bk : bv);
    float4 v = ((const float4*)(src + (size_t)lyr * 1024))[tid];
    ((float4*)(out + (size_t)lyr * 3072 + j * 1024))[tid] = v;
}

// ---------- 64x64 transpose + f32->bf16 convert body ----------
__device__ __forceinline__ void tpose_body(float (*tile)[65], const float* __restrict__ in,
                                           u16* __restrict__ out, int R, int C, int r0, int c0, int tid) {
    int rr = tid >> 4, cc = (tid & 15) * 4;
#pragma unroll
    for (int j = 0; j < 4; ++j) {
        float4 v = *(const float4*)&in[(size_t)(r0 + j * 16 + rr) * C + c0 + cc];
        tile[j * 16 + rr][cc]     = v.x;
        tile[j * 16 + rr][cc + 1] = v.y;
        tile[j * 16 + rr][cc + 2] = v.z;
        tile[j * 16 + rr][cc + 3] = v.w;
    }
    __syncthreads();
    int oc = tid >> 3, r8 = (tid & 7) * 8;
#pragma unroll
    for (int j = 0; j < 2; ++j) {
        int ocl = j * 32 + oc;
        s16x8 vv;
#pragma unroll
        for (int e = 0; e < 8; ++e) vv[e] = (short)f2b(tile[r8 + e][ocl]);
        *(s16x8*)&out[(size_t)(c0 + ocl) * R + r0 + r8] = vv;
    }
}

__global__ __launch_bounds__(256) void transpose_cvt64k(const float* __restrict__ in, u16* __restrict__ out,
                                                        int R, int C) {
    __shared__ float tile[64][65];
    tpose_body(tile, in, out, R, C, blockIdx.y * 64, blockIdx.x * 64, threadIdx.x);
}

// ---------- all of one layer's weights, transposed+converted, one launch ----------
__global__ __launch_bounds__(256) void transpose_layer(
    const float* __restrict__ mw, const float* __restrict__ wq, const float* __restrict__ wk,
    const float* __restrict__ wv, const float* __restrict__ wo, const float* __restrict__ f1,
    const float* __restrict__ f2,
    u16* __restrict__ modT, u16* __restrict__ qkvT, u16* __restrict__ woT,
    u16* __restrict__ f1T, u16* __restrict__ f2T) {
    __shared__ float tile[64][65];
    int bid = blockIdx.x, tid = threadIdx.x;
    const float* src; u16* dst; int R, C, tloc;
    if (bid < 1536)      { src = mw; dst = modT;               R = 1024; C = 6144; tloc = bid; }
    else if (bid < 1792) { src = wq; dst = qkvT;               R = 1024; C = 1024; tloc = bid - 1536; }
    else if (bid < 2048) { src = wk; dst = qkvT + 1024 * 1024; R = 1024; C = 1024; tloc = bid - 1792; }
    else if (bid < 2304) { src = wv; dst = qkvT + 2048 * 1024; R = 1024; C = 1024; tloc = bid - 2048; }
    else if (bid < 2560) { src = wo; dst = woT;                R = 1024; C = 1024; tloc = bid - 2304; }
    else if (bid < 3584) { src = f1; dst = f1T;                R = 1024; C = 4096; tloc = bid - 2560; }
    else                 { src = f2; dst = f2T;                R = 4096; C = 1024; tloc = bid - 3584; }
    int tx = C >> 6;
    int ty = tloc / tx, txi = tloc - ty * tx;
    tpose_body(tile, src, dst, R, C, ty * 64, txi * 64, tid);
}

// ---------- LayerNorm + modulate: hx = ln(x)*(1+sc)+sh -> bf16 ----------
__global__ __launch_bounds__(256) void ln_mod_kernel(const float* __restrict__ x, const float* __restrict__ modv,
                                                     int mod_ld, int sh_off, int sc_off, u16* __restrict__ out) {
    int row = blockIdx.x, tid = threadIdx.x, b = row >> 8;
    float4 xv = ((const float4*)(x + (size_t)row * 1024))[tid];
    float s = xv.x + xv.y + xv.z + xv.w;
    float s2 = xv.x * xv.x + xv.y * xv.y + xv.z * xv.z + xv.w * xv.w;
#pragma unroll
    for (int d = 1; d < 64; d <<= 1) { s += __shfl_xor(s, d); s2 += __shfl_xor(s2, d); }
    __shared__ float red[8];
    int w = tid >> 6;
    if ((tid & 63) == 0) { red[w] = s; red[4 + w] = s2; }
    __syncthreads();
    s = red[0] + red[1] + red[2] + red[3];
    s2 = red[4] + red[5] + red[6] + red[7];
    float mu = s * (1.f / 1024.f);
    float rs = rsqrtf(s2 * (1.f / 1024.f) - mu * mu + 1e-5f);
    const float* shp = modv + (size_t)b * mod_ld + sh_off;
    const float* scp = modv + (size_t)b * mod_ld + sc_off;
    float4 sh4 = ((const float4*)shp)[tid];
    float4 sc4 = ((const float4*)scp)[tid];
    u16 o0 = f2b((xv.x - mu) * rs * (1.f + sc4.x) + sh4.x);
    u16 o1 = f2b((xv.y - mu) * rs * (1.f + sc4.y) + sh4.y);
    u16 o2 = f2b((xv.z - mu) * rs * (1.f + sc4.z) + sh4.z);
    u16 o3 = f2b((xv.w - mu) * rs * (1.f + sc4.w) + sh4.w);
    unsigned long long pk = (unsigned long long)o0 | ((unsigned long long)o1 << 16) |
                            ((unsigned long long)o2 << 32) | ((unsigned long long)o3 << 48);
    *(unsigned long long*)&out[(size_t)row * 1024 + tid * 4] = pk;
}

// =====================================================================
// gemm8: pipelined GEMM, BM=256 x BN=128, BK=64, 512 thr (8 waves 4x2),
// 3 LDS buffers, counted vmcnt, st-swizzled LDS (byte ^= ((byte>>9)&1)<<5).
// C = A(MxK,bf16) * Bt(NxK,bf16)^T. M%256==0, N%128==0, K%64==0, grid%8==0.
// EPI: 1 bf16+bias; 2 f32+bias+pos; 3 residual gate; 4 gelu bf16
// =====================================================================
template <int EPI>
__global__ __launch_bounds__(512, 1) void gemm8(
    const u16* __restrict__ A, int lda, const u16* __restrict__ Bt, int ldb,
    int M, int N, int K, const float* __restrict__ bias,
    float* __restrict__ outF, u16* __restrict__ outB, int ldc,
    const float* __restrict__ aux1, const float* __restrict__ aux2, int gateOff) {
    __shared__ u16 As[3][256 * 64];
    __shared__ u16 Bs[3][128 * 64];

    const int tid = threadIdx.x, w = tid >> 6, l = tid & 63;
    const int wm = w >> 1, wn = w & 1;

    const int nbn = N >> 7;
    const int nwg = gridDim.x;
    const int orig = blockIdx.x;
    const int cpx = nwg >> 3;                       // grid % 8 == 0 guaranteed
    const int wg = (orig & 7) * cpx + (orig >> 3);  // XCD-chunked swizzle (T1)
    const int bm = wg / nbn, bn = wg - bm * nbn;
    const int row0 = bm << 8, col0 = bn << 7;

    const int NT = K >> 6;

    // staging coords: thread -> (srow 0..63, 16B slot 0..7); swizzled global k-slot
    const int srow = tid >> 3, sslot = tid & 7;
    const int ksl = sslot ^ (((srow >> 2) & 1) << 1);
    const u16* gA = A + (size_t)(row0 + srow) * lda + ksl * 8;
    const u16* gB = Bt + (size_t)(col0 + srow) * ldb + ksl * 8;
    const int lOff = srow * 64 + sslot * 8;

    // fragment coords
    const int fr = l & 15, fg = l >> 4;
    const int arow = wm * 64 + fr;
    const int brow = wn * 64 + fr;

    f32x4 acc[4][4];
#pragma unroll
    for (int m = 0; m < 4; ++m)
#pragma unroll
        for (int n = 0; n < 4; ++n) acc[m][n] = (f32x4){0.f, 0.f, 0.f, 0.f};

    // prologue: tile0 full (A0-3,B0-1), tile1 A0-2
    {
        u16* a0 = &As[0][lOff];
        u16* b0 = &Bs[0][lOff];
#pragma unroll
        for (int a = 0; a < 4; ++a) gload16(gA + (size_t)a * 64 * lda, a0 + a * 4096);
#pragma unroll
        for (int b = 0; b < 2; ++b) gload16(gB + (size_t)b * 64 * ldb, b0 + b * 4096);
        if (NT > 1) {
            u16* a1 = &As[1][lOff];
#pragma unroll
            for (int a = 0; a < 3; ++a) gload16(gA + (size_t)a * 64 * lda + 64, a1 + a * 4096);
        }
    }
    if (NT > 1) { asm volatile("s_waitcnt vmcnt(3)" ::: "memory"); }
    else        { asm volatile("s_waitcnt vmcnt(0)" ::: "memory"); }
    __builtin_amdgcn_s_barrier();
    __builtin_amdgcn_sched_barrier(0);

    int q = 0;
    for (int t = 0; t < NT; ++t) {
        const u16* ca = As[q];
        const u16* cb = Bs[q];
        const int q1 = (q == 2) ? 0 : q + 1;
        const int q2 = (q1 == 2) ? 0 : q1 + 1;

        s16x8 af[4][2], bf[4][2];
        // ---- phase 0: read A(all m) + B(n0,n1); stage t+1 A3,B0,B1 ----
#pragma unroll
        for (int m = 0; m < 4; ++m) {
            int r = arow + m * 16;
            int psb = fg ^ (((r >> 2) & 1) << 1);
            af[m][0] = *(const s16x8*)(ca + r * 64 + psb * 8);
            af[m][1] = *(const s16x8*)(ca + r * 64 + psb * 8 + 32);
        }
#pragma unroll
        for (int n = 0; n < 2; ++n) {
            int r = brow + n * 16;
            int psb = fg ^ (((r >> 2) & 1) << 1);
            bf[n][0] = *(const s16x8*)(cb + r * 64 + psb * 8);
            bf[n][1] = *(const s16x8*)(cb + r * 64 + psb * 8 + 32);
        }
        if (t + 1 < NT) {
            gload16(gA + (size_t)(3 * 64) * lda + (size_t)(t + 1) * 64, &As[q1][lOff] + 3 * 4096);
            gload16(gB + (size_t)(t + 1) * 64, &Bs[q1][lOff]);
            gload16(gB + (size_t)(1 * 64) * ldb + (size_t)(t + 1) * 64, &Bs[q1][lOff] + 4096);
        }
        __builtin_amdgcn_s_barrier();
        __builtin_amdgcn_s_setprio(1);
#pragma unroll
        for (int m = 0; m < 4; ++m)
#pragma unroll
            for (int n = 0; n < 2; ++n) {
                acc[m][n] = mfma16(af[m][0], bf[n][0], acc[m][n]);
                acc[m][n] = mfma16(af[m][1], bf[n][1], acc[m][n]);
            }
        __builtin_amdgcn_s_setprio(0);
        __builtin_amdgcn_s_barrier();
        // ---- phase 1: read B(n2,n3); stage t+2 A0,A1,A2 ----
#pragma unroll
        for (int n = 0; n < 2; ++n) {
            int r = brow + (n + 2) * 16;
            int psb = fg ^ (((r >> 2) & 1) << 1);
            bf[n + 2][0] = *(const s16x8*)(cb + r * 64 + psb * 8);
            bf[n + 2][1] = *(const s16x8*)(cb + r * 64 + psb * 8 + 32);
        }
        if (t + 2 < NT) {
#pragma unroll
            for (int a = 0; a < 3; ++a)
                gload16(gA + (size_t)a * 64 * lda + (size_t)(t + 2) * 64, &As[q2][lOff] + a * 4096);
        }
        __builtin_amdgcn_s_barrier();
        __builtin_amdgcn_s_setprio(1);
#pragma unroll
        for (int m = 0; m < 4; ++m)
#pragma unroll
            for (int n = 2; n < 4; ++n) {
                acc[m][n] = mfma16(af[m][0], bf[n][0], acc[m][n]);
                acc[m][n] = mfma16(af[m][1], bf[n][1], acc[m][n]);
            }
        __builtin_amdgcn_s_setprio(0);
        // ---- tile boundary: counted vmcnt, never 0 in steady state ----
        if (t < NT - 2)       { asm volatile("s_waitcnt vmcnt(3)" ::: "memory"); }
        else if (t == NT - 2) { asm volatile("s_waitcnt vmcnt(0)" ::: "memory"); }
        if (t < NT - 1) {
            __builtin_amdgcn_s_barrier();
            __builtin_amdgcn_sched_barrier(0);
        }
        q = q1;
    }

    // epilogue
    const int erow = row0 + wm * 64 + fg * 4;
    const int ecol = col0 + wn * 64 + fr;
#pragma unroll
    for (int m = 0; m < 4; ++m) {
#pragma unroll
        for (int n = 0; n < 4; ++n) {
#pragma unroll
            for (int r = 0; r < 4; ++r) {
                int row = erow + m * 16 + r;
                int col = ecol + n * 16;
                float v = acc[m][n][r];
                if constexpr (EPI == 1) {
                    outB[(size_t)row * ldc + col] = f2b(v + bias[col]);
                } else if constexpr (EPI == 2) {
                    outF[(size_t)row * ldc + col] = v + bias[col] + aux1[(size_t)(row & 255) * 1024 + col];
                } else if constexpr (EPI == 3) {
                    outF[(size_t)row * ldc + col] =
                        aux1[(size_t)row * ldc + col] +
                        aux2[(size_t)(row >> 8) * 6144 + gateOff + col] * (v + bias[col]);
                } else {  // EPI == 4: exact gelu -> bf16
                    float xg = v + bias[col];
                    outB[(size_t)row * ldc + col] = f2b(0.5f * xg * (1.f + erff(xg * 0.70710678118654752f)));
                }
            }
        }
    }
}

// ---------- small GEMM (m97-style 128x128): for M=32 mod GEMMs + final ----------
// EPI 0: outF = acc + bias[col];  EPI 5: unpatchify scatter f32
template <int EPI>
__global__ __launch_bounds__(256, 2) void gemm_k(
    const u16* __restrict__ A, int lda, const u16* __restrict__ Bt, int ldb,
    int M, int N, int K, const float* __restrict__ bias,
    float* outF, u16* __restrict__ outB, int ldc) {
    __shared__ u16 Asl[128 * 32];
    __shared__ u16 Bsl[128 * 32];
    const int tid = threadIdx.x, w = tid >> 6, l = tid & 63;
    const int row0 = blockIdx.y * 128, col0 = blockIdx.x * 128;
    const int wm = w >> 1, wn = w & 1;

    f32x4 acc[4][4];
#pragma unroll
    for (int m = 0; m < 4; ++m)
#pragma unroll
        for (int n = 0; n < 4; ++n) acc[m][n] = (f32x4){0.f, 0.f, 0.f, 0.f};

    const int rA0 = w * 16 + (l >> 2), rA1 = rA0 + 64;
    const int kc = (l & 3) * 8;
    int gr0 = row0 + rA0; if (gr0 > M - 1) gr0 = M - 1;
    int gr1 = row0 + rA1; if (gr1 > M - 1) gr1 = M - 1;
    const u16* a0 = A + (size_t)gr0 * lda + kc;
    const u16* a1 = A + (size_t)gr1 * lda + kc;
    const u16* b0 = Bt + (size_t)(col0 + rA0) * ldb + kc;
    const u16* b1 = Bt + (size_t)(col0 + rA1) * ldb + kc;
    u16* la0 = &Asl[rA0 * 32 + kc];
    u16* la1 = &Asl[rA1 * 32 + kc];
    u16* lb0 = &Bsl[rA0 * 32 + kc];
    u16* lb1 = &Bsl[rA1 * 32 + kc];

    for (int k0 = 0; k0 < K; k0 += 32) {
        __syncthreads();
        gload16(a0 + k0, la0);
        gload16(a1 + k0, la1);
        gload16(b0 + k0, lb0);
        gload16(b1 + k0, lb1);
        __syncthreads();
        s16x8 af[4], bfr[4];
#pragma unroll
        for (int m = 0; m < 4; ++m)
            af[m] = *(const s16x8*)&Asl[(wm * 64 + m * 16 + (l & 15)) * 32 + (l >> 4) * 8];
#pragma unroll
        for (int n = 0; n < 4; ++n)
            bfr[n] = *(const s16x8*)&Bsl[(wn * 64 + n * 16 + (l & 15)) * 32 + (l >> 4) * 8];
#pragma unroll
        for (int m = 0; m < 4; ++m)
#pragma unroll
            for (int n = 0; n < 4; ++n) acc[m][n] = mfma16(af[m], bfr[n], acc[m][n]);
    }

#pragma unroll
    for (int m = 0; m < 4; ++m) {
#pragma unroll
        for (int n = 0; n < 4; ++n) {
#pragma unroll
            for (int r = 0; r < 4; ++r) {
                int row = row0 + wm * 64 + m * 16 + (l >> 4) * 4 + r;
                if (row >= M) continue;
                int col = col0 + wn * 64 + n * 16 + (l & 15);
                float v = acc[m][n][r];
                if constexpr (EPI == 0) {
                    outF[(size_t)row * ldc + col] = v + bias[col];
                } else {  // EPI == 5: unpatchify
                    float xg = v + bias[col];
                    int bb = row >> 8, ll = row & 255, hp = ll >> 4, wp = ll & 15;
                    int pp = col >> 6, d = col & 63;
                    outF[(size_t)((bb * 64 + d) * 32 + hp * 2 + (pp >> 1)) * 32 + wp * 2 + (pp & 1)] = xg;
                }
            }
        }
    }
}

// ---------- attention: qkv (8192,3072) bf16 -> obuf (8192,1024) bf16 ----------
__global__ __launch_bounds__(256, 2) void attn_kernel(const u16* __restrict__ qkv, u16* __restrict__ obuf) {
    __shared__ u16 Qs[64 * 64];
    __shared__ u16 Ks[256 * 64];    // reused later as P [qrow][ktok]
    __shared__ u16 VTs[64 * 256];
    int qt = blockIdx.x, h = blockIdx.y, b = blockIdx.z;
    int tid = threadIdx.x, w = tid >> 6, l = tid & 63;
    size_t base = (size_t)b * 256 * 3072;

    {
        int r = tid >> 2;
#pragma unroll
        for (int j = 0; j < 2; ++j) {
            int sg = (tid & 3) + j * 4;
            *(s16x8*)&Qs[r * 64 + sg * 8] =
                *(const s16x8*)&qkv[base + (size_t)(qt * 64 + r) * 3072 + h * 64 + sg * 8];
        }
    }
#pragma unroll
    for (int j = 0; j < 8; ++j) {
        int i = tid + j * 256;
        int r = i >> 3, sg = i & 7;
        *(s16x8*)&Ks[r * 64 + sg * 8] =
            *(const s16x8*)&qkv[base + (size_t)r * 3072 + 1024 + h * 64 + sg * 8];
    }
#pragma unroll
    for (int j = 0; j < 8; ++j) {
        int i = tid + j * 256;
        int r = i >> 3, sg = i & 7;
        s16x8 v = *(const s16x8*)&qkv[base + (size_t)r * 3072 + 2048 + h * 64 + sg * 8];
#pragma unroll
        for (int e = 0; e < 8; ++e) VTs[(sg * 8 + e) * 256 + r] = ((const u16*)&v)[e];
    }
    __syncthreads();

    s16x8 aq0 = *(const s16x8*)&Qs[(w * 16 + (l & 15)) * 64 + (l >> 4) * 8];
    s16x8 aq1 = *(const s16x8*)&Qs[(w * 16 + (l & 15)) * 64 + 32 + (l >> 4) * 8];
    f32x4 sf[16];
#pragma unroll
    for (int cf = 0; cf < 16; ++cf) {
        f32x4 a = (f32x4){0.f, 0.f, 0.f, 0.f};
        s16x8 bk0 = *(const s16x8*)&Ks[(cf * 16 + (l & 15)) * 64 + (l >> 4) * 8];
        s16x8 bk1 = *(const s16x8*)&Ks[(cf * 16 + (l & 15)) * 64 + 32 + (l >> 4) * 8];
        a = mfma16(aq0, bk0, a);
        a = mfma16(aq1, bk1, a);
        sf[cf] = a * 0.125f;
    }
    __syncthreads();

#pragma unroll
    for (int r = 0; r < 4; ++r) {
        float m = -1e30f;
#pragma unroll
        for (int cf = 0; cf < 16; ++cf) m = fmaxf(m, sf[cf][r]);
#pragma unroll
        for (int d = 1; d < 16; d <<= 1) m = fmaxf(m, __shfl_xor(m, d));
        float sm = 0.f;
#pragma unroll
        for (int cf = 0; cf < 16; ++cf) { float e = __expf(sf[cf][r] - m); sf[cf][r] = e; sm += e; }
#pragma unroll
        for (int d = 1; d < 16; d <<= 1) sm += __shfl_xor(sm, d);
        float inv = 1.f / sm;
        int rl = w * 16 + (l >> 4) * 4 + r;
#pragma unroll
        for (int cf = 0; cf < 16; ++cf) Ks[rl * 256 + cf * 16 + (l & 15)] = f2b(sf[cf][r] * inv);
    }
    __syncthreads();

    f32x4 oacc[4];
#pragma unroll
    for (int cf = 0; cf < 4; ++cf) oacc[cf] = (f32x4){0.f, 0.f, 0.f, 0.f};
#pragma unroll
    for (int ks = 0; ks < 8; ++ks) {
        s16x8 ap = *(const s16x8*)&Ks[(w * 16 + (l & 15)) * 256 + ks * 32 + (l >> 4) * 8];
#pragma unroll
        for (int cf = 0; cf < 4; ++cf) {
            s16x8 bv = *(const s16x8*)&VTs[(cf * 16 + (l & 15)) * 256 + ks * 32 + (l >> 4) * 8];
            oacc[cf] = mfma16(ap, bv, oacc[cf]);
        }
    }
    size_t orow0 = (size_t)(b * 256 + qt * 64 + w * 16);
#pragma unroll
    for (int cf = 0; cf < 4; ++cf)
#pragma unroll
        for (int r = 0; r < 4; ++r) {
            int rr = (l >> 4) * 4 + r;
            obuf[(orow0 + rr) * 1024 + h * 64 + cf * 16 + (l & 15)] = f2b(oacc[cf][r]);
        }
}

// ---------- host ----------
extern "C" void kernel_launch(void* const* d_in, const int* in_sizes, int n_in,
                              void* d_out, int out_size, void* d_ws, size_t ws_size,
                              hipStream_t stream) {
    (void)in_sizes; (void)n_in; (void)out_size; (void)ws_size;
    const float* x         = (const float*)d_in[0];
    const int*   y         = (const int*)d_in[1];
    const int*   t         = (const int*)d_in[2];
    const float* proj_w    = (const float*)d_in[3];
    const float* proj_b    = (const float*)d_in[4];
    const float* pos_embed = (const float*)d_in[5];
    const float* emb_table = (const float*)d_in[6];
    const float* blk_mod_w = (const float*)d_in[7];
    const float* blk_mod_b = (const float*)d_in[8];
    const float* blk_wq    = (const float*)d_in[9];
    const float* blk_bq    = (const float*)d_in[10];
    const float* blk_wk    = (const float*)d_in[11];
    const float* blk_bk    = (const float*)d_in[12];
    const float* blk_wv    = (const float*)d_in[13];
    const float* blk_bv    = (const float*)d_in[14];
    const float* blk_wo    = (const float*)d_in[15];
    const float* blk_bo    = (const float*)d_in[16];
    const float* blk_f1w   = (const float*)d_in[17];
    const float* blk_f1b   = (const float*)d_in[18];
    const float* blk_f2w   = (const float*)d_in[19];
    const float* blk_f2b   = (const float*)d_in[20];
    const float* fin_mod_w = (const float*)d_in[21];
    const float* fin_mod_b = (const float*)d_in[22];
    const float* fin_out_w = (const float*)d_in[23];
    const float* fin_out_b = (const float*)d_in[24];
    float* out = (float*)d_out;

    char* ws = (char*)d_ws;
    size_t off = 0;
    auto alloc = [&](size_t bytes) -> char* {
        char* p = ws + off;
        off += (bytes + 255) & ~(size_t)255;
        return p;
    };
    float* xc    = (float*)alloc(8192ull * 1024 * 4);
    u16*   hx    = (u16*)alloc(8192ull * 1024 * 2);
    u16*   qkvb  = (u16*)alloc(8192ull * 3072 * 2);
    u16*   obufp = (u16*)alloc(8192ull * 1024 * 2);
    u16*   h1    = (u16*)alloc(8192ull * 4096 * 2);
    u16*   patchA= (u16*)alloc(8192ull * 256 * 2);
    u16*   cact  = (u16*)alloc(32ull * 1024 * 2);
    float* modb  = (float*)alloc(32ull * 6144 * 4);
    float* fmod  = (float*)alloc(32ull * 2048 * 4);
    float* bqkv  = (float*)alloc(12ull * 3072 * 4);
    u16*   projT = (u16*)alloc(1024ull * 256 * 2);
    u16*   fmT   = (u16*)alloc(2048ull * 1024 * 2);
    u16*   foT   = (u16*)alloc(256ull * 1024 * 2);
    u16*   modT  = (u16*)alloc(6144ull * 1024 * 2);
    u16*   qkvT  = (u16*)alloc(3072ull * 1024 * 2);
    u16*   woT   = (u16*)alloc(1024ull * 1024 * 2);
    u16*   f1T   = (u16*)alloc(4096ull * 1024 * 2);
    u16*   f2T   = (u16*)alloc(1024ull * 4096 * 2);

    patchify_kernel<<<8192, 256, 0, stream>>>(x, patchA);
    cact_kernel<<<32, 256, 0, stream>>>(t, y, emb_table, cact);
    bcat_kernel<<<dim3(12, 3), 256, 0, stream>>>(blk_bq, blk_bk, blk_bv, bqkv);
    transpose_cvt64k<<<dim3(16, 4), 256, 0, stream>>>(proj_w, projT, 256, 1024);
    transpose_cvt64k<<<dim3(32, 16), 256, 0, stream>>>(fin_mod_w, fmT, 1024, 2048);
    transpose_cvt64k<<<dim3(4, 16), 256, 0, stream>>>(fin_out_w, foT, 1024, 256);

    // tok = patchA @ proj_w + b + pos  -> xc f32   (M=8192,N=1024,K=256)
    gemm8<2><<<256, 512, 0, stream>>>(patchA, 256, projT, 256, 8192, 1024, 256,
                                      proj_b, xc, nullptr, 1024, pos_embed, nullptr, 0);
    // fmod = c_act @ fin_mod_w + b
    gemm_k<0><<<dim3(16, 1), 256, 0, stream>>>(cact, 1024, fmT, 1024, 32, 2048, 1024,
                                               fin_mod_b, fmod, nullptr, 2048);

    for (int i = 0; i < 12; ++i) {
        transpose_layer<<<4608, 256, 0, stream>>>(
            blk_mod_w + (size_t)i * 1024 * 6144,
            blk_wq + (size_t)i * 1024 * 1024, blk_wk + (size_t)i * 1024 * 1024,
            blk_wv + (size_t)i * 1024 * 1024, blk_wo + (size_t)i * 1024 * 1024,
            blk_f1w + (size_t)i * 1024 * 4096, blk_f2w + (size_t)i * 4096 * 1024,
            modT, qkvT, woT, f1T, f2T);

        // mod = c_act @ mod_w + mod_b   (32 x 6144)
        gemm_k<0><<<dim3(48, 1), 256, 0, stream>>>(cact, 1024, modT, 1024, 32, 6144, 1024,
                                                   blk_mod_b + (size_t)i * 6144, modb, nullptr, 6144);
        // hx = ln(xc)*(1+sc_a)+sh_a
        ln_mod_kernel<<<8192, 256, 0, stream>>>(xc, modb, 6144, 0, 1024, hx);
        // qkv = hx @ [wq|wk|wv] + biases  -> bf16
        gemm8<1><<<768, 512, 0, stream>>>(hx, 1024, qkvT, 1024, 8192, 3072, 1024,
                                          bqkv + (size_t)i * 3072, nullptr, qkvb, 3072,
                                          nullptr, nullptr, 0);
        attn_kernel<<<dim3(4, 16, 32), 256, 0, stream>>>(qkvb, obufp);
        // xc += g_a * (o @ wo + bo)
        gemm8<3><<<256, 512, 0, stream>>>(obufp, 1024, woT, 1024, 8192, 1024, 1024,
                                          blk_bo + (size_t)i * 1024, xc, nullptr, 1024,
                                          xc, modb, 2048);
        // hx = ln(xc)*(1+sc_m)+sh_m
        ln_mod_kernel<<<8192, 256, 0, stream>>>(xc, modb, 6144, 3072, 4096, hx);
        // h1 = gelu(hx @ f1 + b1)
        gemm8<4><<<1024, 512, 0, stream>>>(hx, 1024, f1T, 1024, 8192, 4096, 1024,
                                           blk_f1b + (size_t)i * 4096, nullptr, h1, 4096,
                                           nullptr, nullptr, 0);
        // xc += g_m * (h1 @ f2 + b2)
        gemm8<3><<<256, 512, 0, stream>>>(h1, 4096, f2T, 4096, 8192, 1024, 4096,
                                          blk_f2b + (size_t)i * 1024, xc, nullptr, 1024,
                                          xc, modb, 5120);
    }
    // final: hx = ln(xc)*(1+sc)+sh ; out = unpatchify(hx @ fin_out_w + b)
    ln_mod_kernel<<<8192, 256, 0, stream>>>(xc, fmod, 2048, 0, 1024, hx);
    gemm_k<5><<<dim3(2, 64), 256, 0, stream>>>(hx, 1024, foT, 1024, 8192, 256, 1024,
                                               fin_out_b, out, nullptr, 256);
}